// Round 1
// baseline (83.295 us; speedup 1.0000x reference)
//
#include <hip/hip_runtime.h>

// B=8, N=1e6 vertices, each vertex = 6 f32 (pos.xyz, nrm.xyz).
// out[b,n] = [ (T@[p,1]).xyz / w , normalize(R@n) ]  with R = T[:3,:3].
// Memory-bound: 192MB in + 192MB out. One thread = 2 vertices = 3x float4 in/out.

__global__ __launch_bounds__(256)
void GPUBatchProcessor_68186900791881_kernel(const float* __restrict__ verts,
                                             const float* __restrict__ xf,
                                             float* __restrict__ out,
                                             int ppb /* pairs per batch = N/2 */)
{
    int i = blockIdx.x * blockDim.x + threadIdx.x;
    if (i >= ppb) return;
    int b = blockIdx.y;  // wave-uniform batch index

    // 4x4 transform, row-major: 4 aligned float4 loads (L1/L2 resident)
    const float4* T = reinterpret_cast<const float4*>(xf + (size_t)b * 16);
    const float4 r0 = T[0], r1 = T[1], r2 = T[2], r3 = T[3];

    size_t base = ((size_t)b * (size_t)ppb + (size_t)i) * 12;  // float offset
    const float4* vin = reinterpret_cast<const float4*>(verts + base);
    const float4 q0 = vin[0], q1 = vin[1], q2 = vin[2];

    // vertex 0: pos(q0.x,q0.y,q0.z) nrm(q0.w,q1.x,q1.y)
    // vertex 1: pos(q1.z,q1.w,q2.x) nrm(q2.y,q2.z,q2.w)
    float o[12];
#pragma unroll
    for (int v = 0; v < 2; ++v) {
        float px, py, pz, nx, ny, nz;
        if (v == 0) { px = q0.x; py = q0.y; pz = q0.z; nx = q0.w; ny = q1.x; nz = q1.y; }
        else        { px = q1.z; py = q1.w; pz = q2.x; nx = q2.y; ny = q2.z; nz = q2.w; }

        // position: full 4-row transform, then divide by w (w == 1 in practice)
        float tx = r0.x * px + r0.y * py + r0.z * pz + r0.w;
        float ty = r1.x * px + r1.y * py + r1.z * pz + r1.w;
        float tz = r2.x * px + r2.y * py + r2.z * pz + r2.w;
        float tw = r3.x * px + r3.y * py + r3.z * pz + r3.w;
        float invw = 1.0f / tw;
        tx *= invw; ty *= invw; tz *= invw;

        // normal: 3x3 rotate + renormalize
        float mx = r0.x * nx + r0.y * ny + r0.z * nz;
        float my = r1.x * nx + r1.y * ny + r1.z * nz;
        float mz = r2.x * nx + r2.y * ny + r2.z * nz;
        float len = fmaxf(sqrtf(mx * mx + my * my + mz * mz), 1e-8f);
        float inv = 1.0f / len;
        mx *= inv; my *= inv; mz *= inv;

        o[v * 6 + 0] = tx; o[v * 6 + 1] = ty; o[v * 6 + 2] = tz;
        o[v * 6 + 3] = mx; o[v * 6 + 4] = my; o[v * 6 + 5] = mz;
    }

    float4* vout = reinterpret_cast<float4*>(out + base);
    vout[0] = make_float4(o[0], o[1], o[2],  o[3]);
    vout[1] = make_float4(o[4], o[5], o[6],  o[7]);
    vout[2] = make_float4(o[8], o[9], o[10], o[11]);
}

extern "C" void kernel_launch(void* const* d_in, const int* in_sizes, int n_in,
                              void* d_out, int out_size, void* d_ws, size_t ws_size,
                              hipStream_t stream) {
    const float* verts = (const float*)d_in[0];      // batch_vertices (B,N,6)
    // d_in[1] = batch_indices — unused by the reference
    const float* xf    = (const float*)d_in[2];      // batch_transforms (B,4,4)
    float*       out   = (float*)d_out;              // (B,N,6) f32

    const int B = in_sizes[2] / 16;
    const long long totalV = (long long)in_sizes[0] / 6;
    const int N = (int)(totalV / B);
    const int ppb = N / 2;  // N is even (1e6)

    dim3 grid((ppb + 255) / 256, B);
    GPUBatchProcessor_68186900791881_kernel<<<grid, 256, 0, stream>>>(verts, xf, out, ppb);
}

// Round 2
// 74.581 us; speedup vs baseline: 1.1168x; 1.1168x over previous
//
#include <hip/hip_runtime.h>

// B=8, N=1e6 vertices/batch, vertex = 6 f32 (pos.xyz, nrm.xyz).
// out[b,n] = [ (T@[p,1]).xyz / w , normalize(R@n) ], R = T[:3,:3].
// Memory-bound (384 MB total). All global traffic is staged through LDS so
// every global load/store is lane-contiguous float4 (16B/lane coalescing).
// The 48B-stride per-vertex access happens in LDS (stride-3 float4 -> all 32
// bank-quads covered per 8-lane group => ~conflict-free).

constexpr int TPB     = 256;
constexpr int F4PT    = 3;            // float4s per thread (= 2 vertices)
constexpr int TILE_F4 = TPB * F4PT;   // 768 float4 = 512 vertices = 12 KB

__global__ __launch_bounds__(TPB)
void GPUBatchProcessor_68186900791881_kernel(const float4* __restrict__ vin,
                                             const float* __restrict__ xf,
                                             float4* __restrict__ vout,
                                             int f4_per_batch,   // N*6/4
                                             int pairs_per_batch) // N/2
{
    __shared__ float4 lds[TILE_F4];
    const int t = threadIdx.x;
    const int b = blockIdx.y;                       // wave-uniform batch
    const long long batchBase = (long long)b * f4_per_batch;
    const int tileF4 = blockIdx.x * TILE_F4;

    // ---- staged coalesced load: lane-contiguous float4 ----
    const float4* src = vin + batchBase;
#pragma unroll
    for (int k = 0; k < F4PT; ++k) {
        int f = tileF4 + k * TPB + t;
        if (f < f4_per_batch) lds[k * TPB + t] = src[f];
    }
    __syncthreads();

    // transform rows (SGPR loads: b is uniform)
    const float4* T = reinterpret_cast<const float4*>(xf) + (size_t)b * 4;
    const float4 r0 = T[0], r1 = T[1], r2 = T[2], r3 = T[3];

    const int p = blockIdx.x * TPB + t;             // pair index within batch
    if (p < pairs_per_batch) {
        const float4 q0 = lds[t * 3 + 0];
        const float4 q1 = lds[t * 3 + 1];
        const float4 q2 = lds[t * 3 + 2];

        float o[12];
#pragma unroll
        for (int v = 0; v < 2; ++v) {
            float px, py, pz, nx, ny, nz;
            if (v == 0) { px = q0.x; py = q0.y; pz = q0.z; nx = q0.w; ny = q1.x; nz = q1.y; }
            else        { px = q1.z; py = q1.w; pz = q2.x; nx = q2.y; ny = q2.z; nz = q2.w; }

            float tx = r0.x * px + r0.y * py + r0.z * pz + r0.w;
            float ty = r1.x * px + r1.y * py + r1.z * pz + r1.w;
            float tz = r2.x * px + r2.y * py + r2.z * pz + r2.w;
            float tw = r3.x * px + r3.y * py + r3.z * pz + r3.w;
            float invw = 1.0f / tw;
            tx *= invw; ty *= invw; tz *= invw;

            float mx = r0.x * nx + r0.y * ny + r0.z * nz;
            float my = r1.x * nx + r1.y * ny + r1.z * nz;
            float mz = r2.x * nx + r2.y * ny + r2.z * nz;
            float len = fmaxf(sqrtf(mx * mx + my * my + mz * mz), 1e-8f);
            float inv = 1.0f / len;
            mx *= inv; my *= inv; mz *= inv;

            o[v * 6 + 0] = tx; o[v * 6 + 1] = ty; o[v * 6 + 2] = tz;
            o[v * 6 + 3] = mx; o[v * 6 + 4] = my; o[v * 6 + 5] = mz;
        }

        lds[t * 3 + 0] = make_float4(o[0], o[1], o[2],  o[3]);
        lds[t * 3 + 1] = make_float4(o[4], o[5], o[6],  o[7]);
        lds[t * 3 + 2] = make_float4(o[8], o[9], o[10], o[11]);
    }
    __syncthreads();

    // ---- staged coalesced store ----
    float4* dst = vout + batchBase;
#pragma unroll
    for (int k = 0; k < F4PT; ++k) {
        int f = tileF4 + k * TPB + t;
        if (f < f4_per_batch) dst[f] = lds[k * TPB + t];
    }
}

extern "C" void kernel_launch(void* const* d_in, const int* in_sizes, int n_in,
                              void* d_out, int out_size, void* d_ws, size_t ws_size,
                              hipStream_t stream) {
    const float* verts = (const float*)d_in[0];   // (B,N,6) f32
    // d_in[1] = batch_indices — unused by the reference
    const float* xf    = (const float*)d_in[2];   // (B,4,4) f32
    float*       out   = (float*)d_out;           // (B,N,6) f32

    const int B = in_sizes[2] / 16;
    const long long totalV = (long long)in_sizes[0] / 6;
    const int N = (int)(totalV / B);              // 1e6
    const int f4_per_batch   = N * 6 / 4;         // 1.5e6 (N*6 divisible by 4)
    const int pairs_per_batch = N / 2;            // 5e5

    const int tiles = (f4_per_batch + TILE_F4 - 1) / TILE_F4;  // 1954
    dim3 grid(tiles, B);
    GPUBatchProcessor_68186900791881_kernel<<<grid, TPB, 0, stream>>>(
        reinterpret_cast<const float4*>(verts), xf,
        reinterpret_cast<float4*>(out), f4_per_batch, pairs_per_batch);
}

// Round 4
// 59.748 us; speedup vs baseline: 1.3941x; 1.2482x over previous
//
#include <hip/hip_runtime.h>

// B=8, N=1e6 vertices/batch, vertex = 6 f32 (pos.xyz, nrm.xyz).
// out[b,n] = [ (T@[p,1]).xyz / w , normalize(R@n) ], R = T[:3,:3].
// Memory-bound (384 MB). Staging: async global->LDS DMA (global_load_lds w16,
// lane-contiguous float4 dest) so loads drain only at the barrier; compute
// reads the 48B-stride pattern from LDS (~conflict-free); stores are staged
// back through LDS and issued as lane-contiguous nontemporal 16B stores
// (output is never re-read; don't thrash the 256MB L3 with a 384MB stream).

constexpr int TPB     = 256;
constexpr int F4PT    = 3;            // float4s per thread (= 2 vertices)
constexpr int TILE_F4 = TPB * F4PT;   // 768 float4 = 512 vertices = 12 KB

typedef const __attribute__((address_space(1))) void* gp_t;   // global
typedef __attribute__((address_space(3))) void*       lp_t;   // LDS
typedef float __attribute__((ext_vector_type(4)))     f32x4;  // native vec4

__global__ __launch_bounds__(TPB)
void GPUBatchProcessor_68186900791881_kernel(const float4* __restrict__ vin,
                                             const float* __restrict__ xf,
                                             float4* __restrict__ vout,
                                             int f4_per_batch,    // N*6/4
                                             int pairs_per_batch) // N/2
{
    __shared__ float4 lds[TILE_F4];
    const int t = threadIdx.x;
    const int b = blockIdx.y;                       // wave-uniform batch
    const long long batchBase = (long long)b * f4_per_batch;
    const int tileF4 = blockIdx.x * TILE_F4;

    // ---- async staged load: global->LDS DMA, lane-contiguous float4 ----
    const float4* src = vin + batchBase;
#pragma unroll
    for (int k = 0; k < F4PT; ++k) {
        int f = tileF4 + k * TPB + t;
        if (f < f4_per_batch) {
            // dest = wave-uniform base + lane*16: layout matches exactly
            __builtin_amdgcn_global_load_lds((gp_t)(src + f),
                                             (lp_t)&lds[k * TPB + t],
                                             16, 0, 0);
        }
    }
    __syncthreads();   // drains vmcnt: all DMA loads landed

    // transform rows (b uniform -> scalar loads)
    const float4* T = reinterpret_cast<const float4*>(xf) + (size_t)b * 4;
    const float4 r0 = T[0], r1 = T[1], r2 = T[2], r3 = T[3];

    const int p = blockIdx.x * TPB + t;             // pair index within batch
    if (p < pairs_per_batch) {
        const float4 q0 = lds[t * 3 + 0];
        const float4 q1 = lds[t * 3 + 1];
        const float4 q2 = lds[t * 3 + 2];

        float o[12];
#pragma unroll
        for (int v = 0; v < 2; ++v) {
            float px, py, pz, nx, ny, nz;
            if (v == 0) { px = q0.x; py = q0.y; pz = q0.z; nx = q0.w; ny = q1.x; nz = q1.y; }
            else        { px = q1.z; py = q1.w; pz = q2.x; nx = q2.y; ny = q2.z; nz = q2.w; }

            float tx = r0.x * px + r0.y * py + r0.z * pz + r0.w;
            float ty = r1.x * px + r1.y * py + r1.z * pz + r1.w;
            float tz = r2.x * px + r2.y * py + r2.z * pz + r2.w;
            float tw = r3.x * px + r3.y * py + r3.z * pz + r3.w;
            float invw = 1.0f / tw;
            tx *= invw; ty *= invw; tz *= invw;

            float mx = r0.x * nx + r0.y * ny + r0.z * nz;
            float my = r1.x * nx + r1.y * ny + r1.z * nz;
            float mz = r2.x * nx + r2.y * ny + r2.z * nz;
            float len = fmaxf(sqrtf(mx * mx + my * my + mz * mz), 1e-8f);
            float inv = 1.0f / len;
            mx *= inv; my *= inv; mz *= inv;

            o[v * 6 + 0] = tx; o[v * 6 + 1] = ty; o[v * 6 + 2] = tz;
            o[v * 6 + 3] = mx; o[v * 6 + 4] = my; o[v * 6 + 5] = mz;
        }

        lds[t * 3 + 0] = make_float4(o[0], o[1], o[2],  o[3]);
        lds[t * 3 + 1] = make_float4(o[4], o[5], o[6],  o[7]);
        lds[t * 3 + 2] = make_float4(o[8], o[9], o[10], o[11]);
    }
    __syncthreads();

    // ---- staged store: lane-contiguous nontemporal 16B ----
    f32x4* dst = reinterpret_cast<f32x4*>(vout + batchBase);
    const f32x4* lsrc = reinterpret_cast<const f32x4*>(lds);
#pragma unroll
    for (int k = 0; k < F4PT; ++k) {
        int f = tileF4 + k * TPB + t;
        if (f < f4_per_batch)
            __builtin_nontemporal_store(lsrc[k * TPB + t], dst + f);
    }
}

extern "C" void kernel_launch(void* const* d_in, const int* in_sizes, int n_in,
                              void* d_out, int out_size, void* d_ws, size_t ws_size,
                              hipStream_t stream) {
    const float* verts = (const float*)d_in[0];   // (B,N,6) f32
    // d_in[1] = batch_indices — unused by the reference
    const float* xf    = (const float*)d_in[2];   // (B,4,4) f32
    float*       out   = (float*)d_out;           // (B,N,6) f32

    const int B = in_sizes[2] / 16;
    const long long totalV = (long long)in_sizes[0] / 6;
    const int N = (int)(totalV / B);              // 1e6
    const int f4_per_batch    = N * 6 / 4;        // 1.5e6
    const int pairs_per_batch = N / 2;            // 5e5

    const int tiles = (f4_per_batch + TILE_F4 - 1) / TILE_F4;  // 1954
    dim3 grid(tiles, B);
    GPUBatchProcessor_68186900791881_kernel<<<grid, TPB, 0, stream>>>(
        reinterpret_cast<const float4*>(verts), xf,
        reinterpret_cast<float4*>(out), f4_per_batch, pairs_per_batch);
}